// Round 3
// baseline (227.489 us; speedup 1.0000x reference)
//
#include <hip/hip_runtime.h>
#include <hip/hip_bf16.h>

#define S_ 512
#define B_ 32
#define D_ 1024
#define F_ 1024

typedef float f32x4 __attribute__((ext_vector_type(4)));
typedef short bf16x8 __attribute__((ext_vector_type(8)));

__device__ __forceinline__ unsigned short f2bf(float f) {
    __hip_bfloat16 h = __float2bfloat16(f);
    return *reinterpret_cast<unsigned short*>(&h);
}

__device__ __forceinline__ float sigmoidf_fast(float x) {
    float e = __builtin_amdgcn_exp2f(x * -1.44269504088896f);
    return __builtin_amdgcn_rcpf(1.0f + e);
}

// ---------------- Kernel V: v = x0 @ [w1|w2]^T + bias, into vbuf[B][2048] ----
__global__ __launch_bounds__(256) void vker(
    const float* __restrict__ x,
    const float* __restrict__ w1w, const float* __restrict__ w1b,
    const float* __restrict__ w2w, const float* __restrict__ w2b,
    float* __restrict__ vbuf)
{
    __shared__ float xs[B_][132];
    __shared__ float wst[64][132];
    int fb = blockIdx.x & 31;
    int ks = blockIdx.x >> 5;
    int k0 = ks * 128;
    int t  = threadIdx.x;
    const float* w = (fb < 16) ? w1w : w2w;
    int fbase = (fb < 16) ? fb * 64 : (fb - 16) * 64;

    #pragma unroll
    for (int i = 0; i < 4; ++i) {
        int q = t + 256 * i;
        int row = q >> 5, c4 = (q & 31) * 4;
        float4 v = *reinterpret_cast<const float4*>(x + (size_t)row * D_ + k0 + c4);
        *reinterpret_cast<float4*>(&xs[row][c4]) = v;
    }
    #pragma unroll
    for (int i = 0; i < 8; ++i) {
        int q = t + 256 * i;
        int row = q >> 5, c4 = (q & 31) * 4;
        float4 v = *reinterpret_cast<const float4*>(w + (size_t)(fbase + row) * D_ + k0 + c4);
        *reinterpret_cast<float4*>(&wst[row][c4]) = v;
    }
    __syncthreads();

    int b   = t >> 3;
    int fl0 = t & 7;
    float acc[8] = {0,0,0,0,0,0,0,0};
    for (int k4 = 0; k4 < 32; ++k4) {
        float4 xv = *reinterpret_cast<const float4*>(&xs[b][k4 * 4]);
        #pragma unroll
        for (int j = 0; j < 8; ++j) {
            float4 wv = *reinterpret_cast<const float4*>(&wst[fl0 + 8 * j][k4 * 4]);
            acc[j] += xv.x * wv.x + xv.y * wv.y + xv.z * wv.z + xv.w * wv.w;
        }
    }
    #pragma unroll
    for (int j = 0; j < 8; ++j) {
        int fg = fb * 64 + fl0 + 8 * j;
        float v = acc[j];
        if (ks == 0) v += (fg < 1024) ? w1b[fg] : w2b[fg - 1024];
        atomicAdd(&vbuf[b * 2048 + fg], v);
    }
}

// ---------------- xcvt: x[S][B][D] f32 -> xb[B][S][D] bf16 ------------------
__global__ __launch_bounds__(256) void xcvt(
    const float* __restrict__ x, unsigned short* __restrict__ xb)
{
    int g = blockIdx.x * 256 + threadIdx.x;        // 2,097,152 threads x 8 elems
    size_t base = (size_t)g * 8;
    int d  = (int)(base & 1023);
    int sb = (int)(base >> 10);                    // s*32 + b
    int b = sb & 31, s = sb >> 5;
    float4 a = *reinterpret_cast<const float4*>(x + base);
    float4 c = *reinterpret_cast<const float4*>(x + base + 4);
    union { unsigned short u[8]; bf16x8 v; } p;
    p.u[0] = f2bf(a.x); p.u[1] = f2bf(a.y); p.u[2] = f2bf(a.z); p.u[3] = f2bf(a.w);
    p.u[4] = f2bf(c.x); p.u[5] = f2bf(c.y); p.u[6] = f2bf(c.z); p.u[7] = f2bf(c.w);
    *reinterpret_cast<bf16x8*>(xb + ((size_t)(b * S_ + s) * D_ + d)) = p.v;
}

// ---------------- maskgen: mbf[b][f][d] = bf16(sigmoid(v1[b,d]*v2[b,f])*mw[f,d])
__global__ __launch_bounds__(256) void maskgen(
    const float* __restrict__ mw, const float* __restrict__ vbuf,
    unsigned short* __restrict__ mbf)
{
    int b  = blockIdx.x & 31;
    int fc = blockIdx.x >> 5;                      // 64 chunks of 16 f-rows
    int t  = threadIdx.x;
    float4 v1 = *reinterpret_cast<const float4*>(vbuf + b * 2048 + t * 4);
    const float* v2p = vbuf + b * 2048 + 1024 + fc * 16;
    #pragma unroll 4
    for (int r = 0; r < 16; ++r) {
        int f = fc * 16 + r;
        float v2 = v2p[r];
        float4 w = *reinterpret_cast<const float4*>(mw + (size_t)f * D_ + t * 4);
        ushort4 p;
        p.x = f2bf(sigmoidf_fast(v1.x * v2) * w.x);
        p.y = f2bf(sigmoidf_fast(v1.y * v2) * w.y);
        p.z = f2bf(sigmoidf_fast(v1.z * v2) * w.z);
        p.w = f2bf(sigmoidf_fast(v1.w * v2) * w.w);
        *reinterpret_cast<ushort4*>(mbf + ((size_t)(b * F_ + f) * D_ + t * 4)) = p;
    }
}

// ---------------- gemm_bf: out[s,b,f] = sum_d xb[b,s,d]*mbf[b,f,d] + mb[f] ---
// m97 structure: 128x128 tile, BK=64, global_load_lds width 16, linear LDS.
__global__ __launch_bounds__(256) void gemm_bf(
    const unsigned short* __restrict__ xb,
    const unsigned short* __restrict__ mbf,
    const float* __restrict__ mb,
    float* __restrict__ out)
{
    __shared__ __align__(16) unsigned short As[128 * 64];
    __shared__ __align__(16) unsigned short Bs[128 * 64];

    int bid = blockIdx.x;
    int b   = bid >> 5;
    int t32 = bid & 31;
    int mt  = t32 & 3;          // s-tile
    int nt  = t32 >> 2;         // f-tile
    int s0 = mt * 128, n0 = nt * 128;

    int tid = threadIdx.x, lane = tid & 63, wid = tid >> 6;
    int wr = (wid >> 1) * 64, wc = (wid & 1) * 64;

    int lrow = lane >> 3;                 // 0..7 (row within 8-row chunk)
    int lcol = (lane & 7) * 8;            // elem offset (16B units)
    const unsigned short* ag = xb  + ((size_t)(b * S_ + s0) * D_) + lcol;
    const unsigned short* bg = mbf + ((size_t)(b * F_ + n0) * D_) + lcol;

    f32x4 acc[4][4] = {};
    for (int kt = 0; kt < 16; ++kt) {
        int k0 = kt * 64;
        __syncthreads();    // previous compute done reading LDS
        #pragma unroll
        for (int i = 0; i < 4; ++i) {
            int rr = (wid * 4 + i) * 8 + lrow;        // tile row 0..127
            __builtin_amdgcn_global_load_lds(
                (const __attribute__((address_space(1))) void*)(ag + (size_t)rr * D_ + k0),
                (__attribute__((address_space(3))) void*)(As + (wid * 4 + i) * 512),
                16, 0, 0);
            __builtin_amdgcn_global_load_lds(
                (const __attribute__((address_space(1))) void*)(bg + (size_t)rr * D_ + k0),
                (__attribute__((address_space(3))) void*)(Bs + (wid * 4 + i) * 512),
                16, 0, 0);
        }
        __syncthreads();    // loads drained (compiler emits vmcnt(0) before barrier)
        #pragma unroll
        for (int kh = 0; kh < 2; ++kh) {
            int ko = (lane >> 4) * 8 + kh * 32;
            bf16x8 af[4], bfr[4];
            #pragma unroll
            for (int m2 = 0; m2 < 4; ++m2)
                af[m2] = *reinterpret_cast<const bf16x8*>(
                    &As[(wr + m2 * 16 + (lane & 15)) * 64 + ko]);
            #pragma unroll
            for (int n2 = 0; n2 < 4; ++n2)
                bfr[n2] = *reinterpret_cast<const bf16x8*>(
                    &Bs[(wc + n2 * 16 + (lane & 15)) * 64 + ko]);
            #pragma unroll
            for (int m2 = 0; m2 < 4; ++m2)
                #pragma unroll
                for (int n2 = 0; n2 < 4; ++n2)
                    acc[m2][n2] = __builtin_amdgcn_mfma_f32_16x16x32_bf16(
                        af[m2], bfr[n2], acc[m2][n2], 0, 0, 0);
        }
    }

    int col = lane & 15, rg = (lane >> 4) * 4;
    float bias[4];
    #pragma unroll
    for (int n2 = 0; n2 < 4; ++n2) bias[n2] = mb[n0 + wc + n2 * 16 + col];
    #pragma unroll
    for (int m2 = 0; m2 < 4; ++m2)
        #pragma unroll
        for (int n2 = 0; n2 < 4; ++n2)
            #pragma unroll
            for (int r = 0; r < 4; ++r) {
                int srow = s0 + wr + m2 * 16 + rg + r;
                out[(size_t)srow * (B_ * F_) + b * F_ + n0 + wc + n2 * 16 + col]
                    = acc[m2][n2][r] + bias[n2];
            }
}

// ---------------- fallback fused gemm (if ws too small) ----------------------
#define LDA 72
__global__ __launch_bounds__(256) void gemm_fused(
    const float* __restrict__ x,
    const float* __restrict__ mw, const float* __restrict__ mb,
    const float* __restrict__ vbuf,
    float* __restrict__ out)
{
    __shared__ __hip_bfloat16 As[128 * LDA];
    __shared__ __hip_bfloat16 Bs[128 * LDA];
    __shared__ float v2s[128];

    int bid = blockIdx.x;
    int b   = bid >> 5;
    int t32 = bid & 31;
    int mt  = t32 & 3;
    int nt  = t32 >> 2;
    int s0 = mt * 128, n0 = nt * 128;

    int tid  = threadIdx.x;
    int lane = tid & 63, wid = tid >> 6;
    int wr = (wid >> 1) * 64;
    int wc = (wid & 1) * 64;

    if (tid < 128) v2s[tid] = vbuf[b * 2048 + 1024 + n0 + tid];

    f32x4 acc[4][4] = {};
    const size_t xbo = (size_t)b * D_;
    for (int kt = 0; kt < 16; ++kt) {
        int k0 = kt * 64;
        __syncthreads();
        #pragma unroll
        for (int i = 0; i < 8; ++i) {
            int q = tid + 256 * i;
            int row = q >> 4;
            int c = (q & 15) * 4;
            float4 v = *reinterpret_cast<const float4*>(
                x + (size_t)(s0 + row) * (B_ * D_) + xbo + k0 + c);
            unsigned long long pk =
                  (unsigned long long)f2bf(v.x)
                | ((unsigned long long)f2bf(v.y) << 16)
                | ((unsigned long long)f2bf(v.z) << 32)
                | ((unsigned long long)f2bf(v.w) << 48);
            *reinterpret_cast<unsigned long long*>(&As[row * LDA + c]) = pk;
        }
        #pragma unroll
        for (int i = 0; i < 8; ++i) {
            int q = tid + 256 * i;
            int n = q >> 4;
            int c = (q & 15) * 4;
            float4 wv = *reinterpret_cast<const float4*>(mw + (size_t)(n0 + n) * D_ + k0 + c);
            float4 v1 = *reinterpret_cast<const float4*>(vbuf + b * 2048 + k0 + c);
            float v2  = v2s[n];
            unsigned long long pk =
                  (unsigned long long)f2bf(sigmoidf_fast(v1.x * v2) * wv.x)
                | ((unsigned long long)f2bf(sigmoidf_fast(v1.y * v2) * wv.y) << 16)
                | ((unsigned long long)f2bf(sigmoidf_fast(v1.z * v2) * wv.z) << 32)
                | ((unsigned long long)f2bf(sigmoidf_fast(v1.w * v2) * wv.w) << 48);
            *reinterpret_cast<unsigned long long*>(&Bs[n * LDA + c]) = pk;
        }
        __syncthreads();
        #pragma unroll
        for (int kh = 0; kh < 2; ++kh) {
            int ko = (lane >> 4) * 8 + kh * 32;
            bf16x8 af[4], bfr[4];
            #pragma unroll
            for (int m2 = 0; m2 < 4; ++m2)
                af[m2] = *reinterpret_cast<const bf16x8*>(
                    &As[(wr + m2 * 16 + (lane & 15)) * LDA + ko]);
            #pragma unroll
            for (int n2 = 0; n2 < 4; ++n2)
                bfr[n2] = *reinterpret_cast<const bf16x8*>(
                    &Bs[(wc + n2 * 16 + (lane & 15)) * LDA + ko]);
            #pragma unroll
            for (int m2 = 0; m2 < 4; ++m2)
                #pragma unroll
                for (int n2 = 0; n2 < 4; ++n2)
                    acc[m2][n2] = __builtin_amdgcn_mfma_f32_16x16x32_bf16(
                        af[m2], bfr[n2], acc[m2][n2], 0, 0, 0);
        }
    }

    int col = lane & 15, rg = (lane >> 4) * 4;
    float bias[4];
    #pragma unroll
    for (int n2 = 0; n2 < 4; ++n2) bias[n2] = mb[n0 + wc + n2 * 16 + col];
    #pragma unroll
    for (int m2 = 0; m2 < 4; ++m2)
        #pragma unroll
        for (int n2 = 0; n2 < 4; ++n2)
            #pragma unroll
            for (int r = 0; r < 4; ++r) {
                int srow = s0 + wr + m2 * 16 + rg + r;
                out[(size_t)srow * (B_ * F_) + b * F_ + n0 + wc + n2 * 16 + col]
                    = acc[m2][n2][r] + bias[n2];
            }
}

extern "C" void kernel_launch(void* const* d_in, const int* in_sizes, int n_in,
                              void* d_out, int out_size, void* d_ws, size_t ws_size,
                              hipStream_t stream) {
    const float* x   = (const float*)d_in[0];
    const float* w1w = (const float*)d_in[1];
    const float* w1b = (const float*)d_in[2];
    const float* w2w = (const float*)d_in[3];
    const float* w2b = (const float*)d_in[4];
    const float* mw  = (const float*)d_in[5];
    const float* mb  = (const float*)d_in[6];
    float* outp = (float*)d_out;

    float* vbuf = (float*)d_ws;                                           // 256 KB
    unsigned short* xb  = (unsigned short*)((char*)d_ws + ((size_t)1 << 20));   // 32 MB
    unsigned short* mbf = (unsigned short*)((char*)d_ws + ((size_t)33 << 20));  // 64 MB
    size_t need = (size_t)97 << 20;

    hipMemsetAsync(vbuf, 0, B_ * 2048 * sizeof(float), stream);
    vker<<<256, 256, 0, stream>>>(x, w1w, w1b, w2w, w2b, vbuf);
    if (ws_size >= need) {
        xcvt<<<8192, 256, 0, stream>>>(x, xb);
        maskgen<<<2048, 256, 0, stream>>>(mw, vbuf, mbf);
        gemm_bf<<<1024, 256, 0, stream>>>(xb, mbf, mb, outp);
    } else {
        gemm_fused<<<1024, 256, 0, stream>>>(x, mw, mb, vbuf, outp);
    }
}